// Round 11
// baseline (73.768 us; speedup 1.0000x reference)
//
#include <hip/hip_runtime.h>
#include <hip/hip_bf16.h>
#include <cfloat>

#define BB 16
#define NN 512
#define DIMX 78
#define NH 6
#define DHH 13
#define QS 16                      // padded head-dim stride for q (f32)
#define KS 16                      // bf16 row stride (ushorts) for k/v
#define NC (NH*3*DHH)              // 234
#define SCALE 0.27735009811261457f // 13^-0.5
#define LAM_A 1.0f
#define LAM_G 0.5f
#define NU 32

typedef unsigned short ushortx;
typedef ushortx ushort8 __attribute__((ext_vector_type(8)));

__device__ __forceinline__ ushortx f2bf(float f) {
  unsigned u = __float_as_uint(f);
  unsigned r = (u + 0x7FFFu + ((u >> 16) & 1u)) >> 16;
  return (ushortx)r;
}
__device__ __forceinline__ float bf2f(ushortx h) {
  return __uint_as_float(((unsigned)h) << 16);
}

// ---------------- QKV projection: (B*N, 78) @ (78, 234) ----------------
// thread = 4 rows x 4 cols register tile; d chunked by 4 with float2 loads
// (all offsets even -> provably 8B-aligned -> halves VMEM instruction count).
__global__ __launch_bounds__(256) void qkv_kernel(
    const float* __restrict__ x, const float* __restrict__ Wqkv,
    float* __restrict__ q, ushortx* __restrict__ kbf, ushortx* __restrict__ vbf) {
  int idx = blockIdx.x * 256 + threadIdx.x;
  const int NQ = 59;
  int rq = idx / NQ, cq = idx % NQ;
  if (rq >= (BB * NN) / 4) return;
  int c0 = cq * 4; if (c0 > NC - 4) c0 = NC - 4;  // c0 even -> float2 ok
  int r0 = rq * 4;
  const float* x0 = x + (size_t)r0 * DIMX;
  const float* wb = Wqkv + c0;

  float acc[4][4];
#pragma unroll
  for (int r = 0; r < 4; ++r)
#pragma unroll
    for (int c = 0; c < 4; ++c) acc[r][c] = 0.f;

#pragma unroll 2
  for (int d0 = 0; d0 < 76; d0 += 4) {
    float2 wA[4], wB[4];
#pragma unroll
    for (int dd = 0; dd < 4; ++dd) {
      wA[dd] = *(const float2*)(wb + (d0 + dd) * NC);
      wB[dd] = *(const float2*)(wb + (d0 + dd) * NC + 2);
    }
    float2 xv[4][2];
#pragma unroll
    for (int r = 0; r < 4; ++r) {
      xv[r][0] = *(const float2*)(x0 + r * DIMX + d0);
      xv[r][1] = *(const float2*)(x0 + r * DIMX + d0 + 2);
    }
#pragma unroll
    for (int dd = 0; dd < 4; ++dd) {
#pragma unroll
      for (int r = 0; r < 4; ++r) {
        float xvv = (dd < 2) ? ((dd & 1) ? xv[r][0].y : xv[r][0].x)
                             : ((dd & 1) ? xv[r][1].y : xv[r][1].x);
        acc[r][0] = fmaf(xvv, wA[dd].x, acc[r][0]);
        acc[r][1] = fmaf(xvv, wA[dd].y, acc[r][1]);
        acc[r][2] = fmaf(xvv, wB[dd].x, acc[r][2]);
        acc[r][3] = fmaf(xvv, wB[dd].y, acc[r][3]);
      }
    }
  }
  // tail d = 76, 77
#pragma unroll
  for (int dd = 0; dd < 2; ++dd) {
    int d = 76 + dd;
    float2 wA = *(const float2*)(wb + d * NC);
    float2 wB = *(const float2*)(wb + d * NC + 2);
#pragma unroll
    for (int r = 0; r < 4; ++r) {
      float xvv = x0[r * DIMX + d];
      acc[r][0] = fmaf(xvv, wA.x, acc[r][0]);
      acc[r][1] = fmaf(xvv, wA.y, acc[r][1]);
      acc[r][2] = fmaf(xvv, wB.x, acc[r][2]);
      acc[r][3] = fmaf(xvv, wB.y, acc[r][3]);
    }
  }

#pragma unroll
  for (int r = 0; r < 4; ++r) {
    int bn = r0 + r;
    int b = bn / NN, n = bn % NN;
#pragma unroll
    for (int c = 0; c < 4; ++c) {
      int col = c0 + c;
      int h  = col / (3 * DHH);
      int rm = col % (3 * DHH);
      int t  = rm / DHH;
      int dd = rm % DHH;
      size_t rowb = ((size_t)b * NH + h) * NN + n;
      if (t == 0)      q[rowb * QS + dd]   = acc[r][c];
      else if (t == 1) kbf[rowb * KS + dd] = f2bf(acc[r][c]);
      else             vbf[rowb * KS + dd] = f2bf(acc[r][c]);
    }
  }
}

// ---------------- Fused masked softmax attention (compacted, bf16 LDS) ----
// grid = 768 blocks; block = 256 (4 waves), 4 blocks/CU. XCD swizzle keeps
// each batch's adj slab in one XCD L2. No max-subtraction (|q.k*scale| ~ 1,
// softmax shift-invariant); jact hoisted to regs per lane.
__global__ __launch_bounds__(256, 4) void attn_kernel(
    const float* __restrict__ q, const ushortx* __restrict__ kbf,
    const ushortx* __restrict__ vbf, const int* __restrict__ mask,
    const float* __restrict__ adj, float* __restrict__ att) {
  __shared__ ushort8 k0s[NN], k1s[NN];
  __shared__ ushort8 v0s[NN], v1s[NN];
  __shared__ short jact[NN];
  __shared__ unsigned char ract[64];
  __shared__ float vsum[DHH];
  __shared__ float vpart_s[2][DHH];
  __shared__ int nact_s, nract_s;

  int d0    = blockIdx.x;
  int orig  = (d0 & 7) * 96 + (d0 >> 3);  // bijective: 768 = 8 XCDs * 96
  int itile = orig & 7;
  int bh    = orig >> 3;                  // b-major: bh = b*NH + h
  int b     = bh / NH;
  int h     = bh % NH;
  int i0    = itile * 64;

  const float*   qb  = q   + (size_t)bh * NN * QS;
  const ushortx* kbb = kbf + (size_t)bh * NN * KS;
  const ushortx* vbb = vbf + (size_t)bh * NN * KS;
  const int* mrow = mask + b * NN;

  int tid  = threadIdx.x;
  int wave = tid >> 6, lane = tid & 63;

  if (wave == 0) {
    // column compaction: lane owns 8 j's, prefix scan over lanes
    unsigned m8 = 0;
#pragma unroll
    for (int t = 0; t < 8; ++t) {
      int j = lane * 8 + t;
      if (mrow[j] != 0) m8 |= (1u << t);
    }
    int cnt = __popc(m8);
    int pre = cnt;
#pragma unroll
    for (int off = 1; off < 64; off <<= 1) {
      int o = __shfl_up(pre, off);
      if (lane >= off) pre += o;
    }
    pre -= cnt;
    int w = pre;
#pragma unroll
    for (int t = 0; t < 8; ++t)
      if ((m8 >> t) & 1) jact[w++] = (short)(lane * 8 + t);
    if (lane == 63) nact_s = pre + cnt;
  } else if (wave == 1) {
    // row compaction for this 64-row tile
    int a = (mrow[i0 + lane] != 0) ? 1 : 0;
    int pre = a;
#pragma unroll
    for (int off = 1; off < 64; off <<= 1) {
      int o = __shfl_up(pre, off);
      if (lane >= off) pre += o;
    }
    pre -= a;
    if (a) ract[pre] = (unsigned char)lane;
    if (lane == 63) nract_s = pre + a;
  } else {
    // waves 2,3: vsum partials over ALL 512 v rows (bf16 src, f32 accum)
    int idx2 = (wave - 2) * 64 + lane;  // 0..127
    float vp[DHH];
#pragma unroll
    for (int d = 0; d < DHH; ++d) vp[d] = 0.f;
#pragma unroll
    for (int rep = 0; rep < 4; ++rep) {
      const ushortx* vr = vbb + (size_t)(idx2 + rep * 128) * KS;
      ushort8 f0 = *(const ushort8*)(vr);
      ushort8 f1 = *(const ushort8*)(vr + 8);
#pragma unroll
      for (int d = 0; d < 8; ++d) vp[d] += bf2f(f0[d]);
#pragma unroll
      for (int d = 0; d < 5; ++d) vp[8 + d] += bf2f(f1[d]);
    }
#pragma unroll
    for (int off = 1; off < 64; off <<= 1)
#pragma unroll
      for (int d = 0; d < DHH; ++d) vp[d] += __shfl_xor(vp[d], off);
    if (lane < DHH) vpart_s[wave - 2][lane] = vp[lane];
  }
  __syncthreads();

  int na = nact_s;
  int nr = nract_s;

  // stage compacted K,V (straight 32B bf16 row copies); zero tails
  for (int t = tid; t < NN; t += 256) {
    if (t < na) {
      int j = jact[t];
      const ushortx* kr = kbb + (size_t)j * KS;
      const ushortx* vr = vbb + (size_t)j * KS;
      k0s[t] = *(const ushort8*)(kr);
      k1s[t] = *(const ushort8*)(kr + 8);
      v0s[t] = *(const ushort8*)(vr);
      v1s[t] = *(const ushort8*)(vr + 8);
    } else {
      ushort8 z = (ushort8)0;
      k0s[t] = z; k1s[t] = z; v0s[t] = z; v1s[t] = z;
      jact[t] = 0;
    }
  }
  if (tid < DHH) vsum[tid] = vpart_s[0][tid] + vpart_s[1][tid];
  __syncthreads();

  // fully-masked rows: uniform softmax over all 512, zero adjacency
  for (int e = tid; e < 64 * DHH; e += 256) {
    int r = e / DHH, d = e % DHH;
    int i = i0 + r;
    if (mrow[i] == 0)
      att[((size_t)b * NN + i) * DIMX + h * DHH + d] = (LAM_A / 512.f) * vsum[d];
  }

  int grp = lane >> 4;
  int li  = lane & 15;

  // hoist active-col indices for this lane (row-invariant)
  int jc[NU];
#pragma unroll
  for (int u = 0; u < NU; ++u)
    if (u * 16 < na) jc[u] = jact[u * 16 + li];

  for (int base = wave * 4; base < nr; base += 16) {
    int ridx = base + grp;
    bool rok = ridx < nr;
    int i = i0 + ract[rok ? ridx : 0];
    const float* qi = qb + (size_t)i * QS;
    float4 q0 = *(const float4*)(qi);
    float4 q1 = *(const float4*)(qi + 4);
    float4 q2 = *(const float4*)(qi + 8);
    float qreg[DHH] = {q0.x*SCALE, q0.y*SCALE, q0.z*SCALE, q0.w*SCALE,
                       q1.x*SCALE, q1.y*SCALE, q1.z*SCALE, q1.w*SCALE,
                       q2.x*SCALE, q2.y*SCALE, q2.z*SCALE, q2.w*SCALE,
                       qi[12]*SCALE};
    const float* adjr = adj + ((size_t)b * NN + i) * NN;

    float s[NU], aj[NU];
    float sum = 0.f;
#pragma unroll
    for (int u = 0; u < NU; ++u) {
      if (u * 16 < na) {  // wave-uniform branch
        int t = u * 16 + li;
        ushort8 ka = k0s[t];
        ushort8 kc = k1s[t];
        aj[u] = adjr[jc[u]];  // prefetched, consumed after softmax
        float dot = 0.f;
#pragma unroll
        for (int d = 0; d < 8; ++d) dot = fmaf(qreg[d], bf2f(ka[d]), dot);
#pragma unroll
        for (int d = 0; d < 5; ++d) dot = fmaf(qreg[8 + d], bf2f(kc[d]), dot);
        // |dot| ~ O(1): exp without max-subtraction is safe; tail -> exp=0
        float p = __expf((t < na) ? dot : -FLT_MAX);
        s[u] = p;
        sum += p;
      }
    }
#pragma unroll
    for (int off = 1; off < 16; off <<= 1) sum += __shfl_xor(sum, off);
    float inv = LAM_A / sum;

    float acc[DHH];
#pragma unroll
    for (int d = 0; d < DHH; ++d) acc[d] = 0.f;
#pragma unroll
    for (int u = 0; u < NU; ++u) {
      if (u * 16 < na) {
        int t = u * 16 + li;
        ushort8 va = v0s[t];
        ushort8 vc = v1s[t];
        float wu = fmaf(LAM_G, aj[u], s[u] * inv);  // tail rows: v==0 -> 0
#pragma unroll
        for (int d = 0; d < 8; ++d) acc[d] = fmaf(wu, bf2f(va[d]), acc[d]);
#pragma unroll
        for (int d = 0; d < 5; ++d) acc[8 + d] = fmaf(wu, bf2f(vc[d]), acc[8 + d]);
      }
    }
#pragma unroll
    for (int off = 1; off < 16; off <<= 1) {
#pragma unroll
      for (int d = 0; d < DHH; ++d) acc[d] += __shfl_xor(acc[d], off);
    }

    if (rok && li == 0) {
#pragma unroll
      for (int d = 0; d < DHH; ++d)
        att[((size_t)b * NN + i) * DIMX + h * DHH + d] = acc[d];
    }
  }
}

// ---------------- Output projection: (B*N,78) @ (78,78) + b ----------------
// block = 320 threads (5 waves), 32 rows/block, thread = 2 rows x 4 cols.
__global__ __launch_bounds__(320) void proj_kernel(
    const float* __restrict__ att, const float* __restrict__ Wout,
    const float* __restrict__ bout, float* __restrict__ out) {
  __shared__ float Ws[DIMX][80];   // padded cols
  __shared__ float as[32][82];     // stride 82: conflict-free row reads
  __shared__ float bs[80];
  int tid = threadIdx.x;
  for (int e = tid; e < DIMX * 80; e += 320) {
    int r = e / 80, c = e % 80;
    Ws[r][c] = (c < DIMX) ? Wout[r * DIMX + c] : 0.f;
  }
  if (tid < 80) bs[tid] = (tid < DIMX) ? bout[tid] : 0.f;
  size_t row0 = (size_t)blockIdx.x * 32;
  for (int e = tid; e < 32 * DIMX; e += 320)
    as[e / DIMX][e % DIMX] = att[row0 * DIMX + e];
  __syncthreads();

  int r2 = tid / 20;   // 0..15 -> rows r2*2, r2*2+1
  int cq = tid % 20;   // 0..19 -> cols cq*4..cq*4+3 (last quad: 2 pad)
  int c0 = cq * 4;
  float acc0[4], acc1[4];
#pragma unroll
  for (int kk = 0; kk < 4; ++kk) { acc0[kk] = bs[c0 + kk]; acc1[kk] = bs[c0 + kk]; }

#pragma unroll 6
  for (int d = 0; d < DIMX; ++d) {
    float4 w = *(const float4*)&Ws[d][c0];
    float a0 = as[r2 * 2 + 0][d];
    float a1 = as[r2 * 2 + 1][d];
    acc0[0] = fmaf(a0, w.x, acc0[0]); acc0[1] = fmaf(a0, w.y, acc0[1]);
    acc0[2] = fmaf(a0, w.z, acc0[2]); acc0[3] = fmaf(a0, w.w, acc0[3]);
    acc1[0] = fmaf(a1, w.x, acc1[0]); acc1[1] = fmaf(a1, w.y, acc1[1]);
    acc1[2] = fmaf(a1, w.z, acc1[2]); acc1[3] = fmaf(a1, w.w, acc1[3]);
  }

  size_t r0o = (row0 + r2 * 2) * (size_t)DIMX;
  *(float2*)&out[r0o + c0]        = make_float2(acc0[0], acc0[1]);
  *(float2*)&out[r0o + DIMX + c0] = make_float2(acc1[0], acc1[1]);
  if (cq < 19) {
    *(float2*)&out[r0o + c0 + 2]        = make_float2(acc0[2], acc0[3]);
    *(float2*)&out[r0o + DIMX + c0 + 2] = make_float2(acc1[2], acc1[3]);
  }
}

extern "C" void kernel_launch(void* const* d_in, const int* in_sizes, int n_in,
                              void* d_out, int out_size, void* d_ws, size_t ws_size,
                              hipStream_t stream) {
  const float* x    = (const float*)d_in[0];
  const int*   mask = (const int*)d_in[1];
  const float* adj  = (const float*)d_in[2];
  const float* Wqkv = (const float*)d_in[3];
  const float* Wout = (const float*)d_in[4];
  const float* bout = (const float*)d_in[5];
  float* out = (float*)d_out;

  const size_t heads_rows = (size_t)BB * NH * NN;           // 49152
  float*   q   = (float*)d_ws;                              // heads_rows*QS f32
  float*   att = q + heads_rows * QS;                       // BB*NN*DIMX f32
  ushortx* kbf = (ushortx*)(att + (size_t)BB * NN * DIMX);  // heads_rows*KS ush
  ushortx* vbf = kbf + heads_rows * KS;

  const int NQ = 59;
  int qkv_threads = (BB * NN / 4) * NQ;
  qkv_kernel<<<(qkv_threads + 255) / 256, 256, 0, stream>>>(x, Wqkv, q, kbf, vbf);
  attn_kernel<<<BB * NH * (NN / 64), 256, 0, stream>>>(q, kbf, vbf, mask, adj, att);
  proj_kernel<<<BB * NN / 32, 320, 0, stream>>>(att, Wout, bout, out);
}

// Round 12
// 59.866 us; speedup vs baseline: 1.2322x; 1.2322x over previous
//
#include <hip/hip_runtime.h>
#include <hip/hip_bf16.h>
#include <cfloat>

#define BB 16
#define NN 512
#define DIMX 78
#define NH 6
#define DHH 13
#define QS 16                      // padded head-dim stride for q (f32)
#define KS 16                      // bf16 row stride (ushorts) for k/v
#define NC (NH*3*DHH)              // 234
#define SCALE 0.27735009811261457f // 13^-0.5
#define LAM_A 1.0f
#define LAM_G 0.5f
#define NU 32

typedef unsigned short ushortx;
typedef ushortx ushort8 __attribute__((ext_vector_type(8)));

__device__ __forceinline__ ushortx f2bf(float f) {
  unsigned u = __float_as_uint(f);
  unsigned r = (u + 0x7FFFu + ((u >> 16) & 1u)) >> 16;
  return (ushortx)r;
}
__device__ __forceinline__ float bf2f(ushortx h) {
  return __uint_as_float(((unsigned)h) << 16);
}

// ---------------- QKV projection: (B*N, 78) @ (78, 234) ----------------
// thread = 4 rows x 4 cols register tile; d chunked by 4 with float2 loads
// (all offsets even -> provably 8B-aligned -> halves VMEM instruction count).
__global__ __launch_bounds__(256) void qkv_kernel(
    const float* __restrict__ x, const float* __restrict__ Wqkv,
    float* __restrict__ q, ushortx* __restrict__ kbf, ushortx* __restrict__ vbf) {
  int idx = blockIdx.x * 256 + threadIdx.x;
  const int NQ = 59;
  int rq = idx / NQ, cq = idx % NQ;
  if (rq >= (BB * NN) / 4) return;
  int c0 = cq * 4; if (c0 > NC - 4) c0 = NC - 4;  // c0 even -> float2 ok
  int r0 = rq * 4;
  const float* x0 = x + (size_t)r0 * DIMX;
  const float* wb = Wqkv + c0;

  float acc[4][4];
#pragma unroll
  for (int r = 0; r < 4; ++r)
#pragma unroll
    for (int c = 0; c < 4; ++c) acc[r][c] = 0.f;

#pragma unroll 2
  for (int d0 = 0; d0 < 76; d0 += 4) {
    float2 wA[4], wB[4];
#pragma unroll
    for (int dd = 0; dd < 4; ++dd) {
      wA[dd] = *(const float2*)(wb + (d0 + dd) * NC);
      wB[dd] = *(const float2*)(wb + (d0 + dd) * NC + 2);
    }
    float2 xv[4][2];
#pragma unroll
    for (int r = 0; r < 4; ++r) {
      xv[r][0] = *(const float2*)(x0 + r * DIMX + d0);
      xv[r][1] = *(const float2*)(x0 + r * DIMX + d0 + 2);
    }
#pragma unroll
    for (int dd = 0; dd < 4; ++dd) {
#pragma unroll
      for (int r = 0; r < 4; ++r) {
        float xvv = (dd < 2) ? ((dd & 1) ? xv[r][0].y : xv[r][0].x)
                             : ((dd & 1) ? xv[r][1].y : xv[r][1].x);
        acc[r][0] = fmaf(xvv, wA[dd].x, acc[r][0]);
        acc[r][1] = fmaf(xvv, wA[dd].y, acc[r][1]);
        acc[r][2] = fmaf(xvv, wB[dd].x, acc[r][2]);
        acc[r][3] = fmaf(xvv, wB[dd].y, acc[r][3]);
      }
    }
  }
  // tail d = 76, 77
#pragma unroll
  for (int dd = 0; dd < 2; ++dd) {
    int d = 76 + dd;
    float2 wA = *(const float2*)(wb + d * NC);
    float2 wB = *(const float2*)(wb + d * NC + 2);
#pragma unroll
    for (int r = 0; r < 4; ++r) {
      float xvv = x0[r * DIMX + d];
      acc[r][0] = fmaf(xvv, wA.x, acc[r][0]);
      acc[r][1] = fmaf(xvv, wA.y, acc[r][1]);
      acc[r][2] = fmaf(xvv, wB.x, acc[r][2]);
      acc[r][3] = fmaf(xvv, wB.y, acc[r][3]);
    }
  }

#pragma unroll
  for (int r = 0; r < 4; ++r) {
    int bn = r0 + r;
    int b = bn / NN, n = bn % NN;
#pragma unroll
    for (int c = 0; c < 4; ++c) {
      int col = c0 + c;
      int h  = col / (3 * DHH);
      int rm = col % (3 * DHH);
      int t  = rm / DHH;
      int dd = rm % DHH;
      size_t rowb = ((size_t)b * NH + h) * NN + n;
      if (t == 0)      q[rowb * QS + dd]   = acc[r][c];
      else if (t == 1) kbf[rowb * KS + dd] = f2bf(acc[r][c]);
      else             vbf[rowb * KS + dd] = f2bf(acc[r][c]);
    }
  }
}

// ---------------- Fused masked softmax attention (compacted, bf16 LDS) ----
// grid = 768 blocks; block = 256 (4 waves), 4 blocks/CU.
// BYTE-IDENTICAL to the proven 61.0us R10 kernel (no jc hoist, with
// max-subtraction): the row loop has ~60 regs headroom; extras spill.
__global__ __launch_bounds__(256, 4) void attn_kernel(
    const float* __restrict__ q, const ushortx* __restrict__ kbf,
    const ushortx* __restrict__ vbf, const int* __restrict__ mask,
    const float* __restrict__ adj, float* __restrict__ att) {
  __shared__ ushort8 k0s[NN], k1s[NN];
  __shared__ ushort8 v0s[NN], v1s[NN];
  __shared__ short jact[NN];
  __shared__ unsigned char ract[64];
  __shared__ float vsum[DHH];
  __shared__ float vpart_s[2][DHH];
  __shared__ int nact_s, nract_s;

  int d0    = blockIdx.x;
  int orig  = (d0 & 7) * 96 + (d0 >> 3);  // bijective: 768 = 8 XCDs * 96
  int itile = orig & 7;
  int bh    = orig >> 3;                  // b-major: bh = b*NH + h
  int b     = bh / NH;
  int h     = bh % NH;
  int i0    = itile * 64;

  const float*   qb  = q   + (size_t)bh * NN * QS;
  const ushortx* kbb = kbf + (size_t)bh * NN * KS;
  const ushortx* vbb = vbf + (size_t)bh * NN * KS;
  const int* mrow = mask + b * NN;

  int tid  = threadIdx.x;
  int wave = tid >> 6, lane = tid & 63;

  if (wave == 0) {
    // column compaction: lane owns 8 j's, prefix scan over lanes
    unsigned m8 = 0;
#pragma unroll
    for (int t = 0; t < 8; ++t) {
      int j = lane * 8 + t;
      if (mrow[j] != 0) m8 |= (1u << t);
    }
    int cnt = __popc(m8);
    int pre = cnt;
#pragma unroll
    for (int off = 1; off < 64; off <<= 1) {
      int o = __shfl_up(pre, off);
      if (lane >= off) pre += o;
    }
    pre -= cnt;
    int w = pre;
#pragma unroll
    for (int t = 0; t < 8; ++t)
      if ((m8 >> t) & 1) jact[w++] = (short)(lane * 8 + t);
    if (lane == 63) nact_s = pre + cnt;
  } else if (wave == 1) {
    // row compaction for this 64-row tile
    int a = (mrow[i0 + lane] != 0) ? 1 : 0;
    int pre = a;
#pragma unroll
    for (int off = 1; off < 64; off <<= 1) {
      int o = __shfl_up(pre, off);
      if (lane >= off) pre += o;
    }
    pre -= a;
    if (a) ract[pre] = (unsigned char)lane;
    if (lane == 63) nract_s = pre + a;
  } else {
    // waves 2,3: vsum partials over ALL 512 v rows (bf16 src, f32 accum)
    int idx2 = (wave - 2) * 64 + lane;  // 0..127
    float vp[DHH];
#pragma unroll
    for (int d = 0; d < DHH; ++d) vp[d] = 0.f;
#pragma unroll
    for (int rep = 0; rep < 4; ++rep) {
      const ushortx* vr = vbb + (size_t)(idx2 + rep * 128) * KS;
      ushort8 f0 = *(const ushort8*)(vr);
      ushort8 f1 = *(const ushort8*)(vr + 8);
#pragma unroll
      for (int d = 0; d < 8; ++d) vp[d] += bf2f(f0[d]);
#pragma unroll
      for (int d = 0; d < 5; ++d) vp[8 + d] += bf2f(f1[d]);
    }
#pragma unroll
    for (int off = 1; off < 64; off <<= 1)
#pragma unroll
      for (int d = 0; d < DHH; ++d) vp[d] += __shfl_xor(vp[d], off);
    if (lane < DHH) vpart_s[wave - 2][lane] = vp[lane];
  }
  __syncthreads();

  int na = nact_s;
  int nr = nract_s;

  // stage compacted K,V (straight 32B bf16 row copies); zero tails
  for (int t = tid; t < NN; t += 256) {
    if (t < na) {
      int j = jact[t];
      const ushortx* kr = kbb + (size_t)j * KS;
      const ushortx* vr = vbb + (size_t)j * KS;
      k0s[t] = *(const ushort8*)(kr);
      k1s[t] = *(const ushort8*)(kr + 8);
      v0s[t] = *(const ushort8*)(vr);
      v1s[t] = *(const ushort8*)(vr + 8);
    } else {
      ushort8 z = (ushort8)0;
      k0s[t] = z; k1s[t] = z; v0s[t] = z; v1s[t] = z;
      jact[t] = 0;
    }
  }
  if (tid < DHH) vsum[tid] = vpart_s[0][tid] + vpart_s[1][tid];
  __syncthreads();

  // fully-masked rows: uniform softmax over all 512, zero adjacency
  for (int e = tid; e < 64 * DHH; e += 256) {
    int r = e / DHH, d = e % DHH;
    int i = i0 + r;
    if (mrow[i] == 0)
      att[((size_t)b * NN + i) * DIMX + h * DHH + d] = (LAM_A / 512.f) * vsum[d];
  }

  int grp = lane >> 4;
  int li  = lane & 15;

  for (int base = wave * 4; base < nr; base += 16) {
    int ridx = base + grp;
    bool rok = ridx < nr;
    int i = i0 + ract[rok ? ridx : 0];
    const float* qi = qb + (size_t)i * QS;
    float4 q0 = *(const float4*)(qi);
    float4 q1 = *(const float4*)(qi + 4);
    float4 q2 = *(const float4*)(qi + 8);
    float qreg[DHH] = {q0.x*SCALE, q0.y*SCALE, q0.z*SCALE, q0.w*SCALE,
                       q1.x*SCALE, q1.y*SCALE, q1.z*SCALE, q1.w*SCALE,
                       q2.x*SCALE, q2.y*SCALE, q2.z*SCALE, q2.w*SCALE,
                       qi[12]*SCALE};
    const float* adjr = adj + ((size_t)b * NN + i) * NN;

    float s[NU], aj[NU];
    float mx = -FLT_MAX;
#pragma unroll
    for (int u = 0; u < NU; ++u) {
      if (u * 16 < na) {  // wave-uniform branch
        int t = u * 16 + li;
        ushort8 ka = k0s[t];
        ushort8 kc = k1s[t];
        aj[u] = adjr[jact[t]];  // prefetched, consumed after softmax
        float dot = 0.f;
#pragma unroll
        for (int d = 0; d < 8; ++d) dot = fmaf(qreg[d], bf2f(ka[d]), dot);
#pragma unroll
        for (int d = 0; d < 5; ++d) dot = fmaf(qreg[8 + d], bf2f(kc[d]), dot);
        s[u] = (t < na) ? dot : -FLT_MAX;
        mx = fmaxf(mx, s[u]);
      }
    }
#pragma unroll
    for (int off = 1; off < 16; off <<= 1) mx = fmaxf(mx, __shfl_xor(mx, off));

    float sum = 0.f;
#pragma unroll
    for (int u = 0; u < NU; ++u) {
      if (u * 16 < na) {
        float p = __expf(s[u] - mx);
        s[u] = p;
        sum += p;
      }
    }
#pragma unroll
    for (int off = 1; off < 16; off <<= 1) sum += __shfl_xor(sum, off);
    float inv = LAM_A / sum;

    float acc[DHH];
#pragma unroll
    for (int d = 0; d < DHH; ++d) acc[d] = 0.f;
#pragma unroll
    for (int u = 0; u < NU; ++u) {
      if (u * 16 < na) {
        int t = u * 16 + li;
        ushort8 va = v0s[t];
        ushort8 vc = v1s[t];
        float wu = fmaf(LAM_G, aj[u], s[u] * inv);  // tail rows: v==0 -> 0
#pragma unroll
        for (int d = 0; d < 8; ++d) acc[d] = fmaf(wu, bf2f(va[d]), acc[d]);
#pragma unroll
        for (int d = 0; d < 5; ++d) acc[8 + d] = fmaf(wu, bf2f(vc[d]), acc[8 + d]);
      }
    }
#pragma unroll
    for (int off = 1; off < 16; off <<= 1) {
#pragma unroll
      for (int d = 0; d < DHH; ++d) acc[d] += __shfl_xor(acc[d], off);
    }

    if (rok && li == 0) {
#pragma unroll
      for (int d = 0; d < DHH; ++d)
        att[((size_t)b * NN + i) * DIMX + h * DHH + d] = acc[d];
    }
  }
}

// ---------------- Output projection: (B*N,78) @ (78,78) + b ----------------
// block = 320 threads (5 waves), 32 rows/block, thread = 2 rows x 4 cols.
__global__ __launch_bounds__(320) void proj_kernel(
    const float* __restrict__ att, const float* __restrict__ Wout,
    const float* __restrict__ bout, float* __restrict__ out) {
  __shared__ float Ws[DIMX][80];   // padded cols
  __shared__ float as[32][82];     // stride 82: conflict-free row reads
  __shared__ float bs[80];
  int tid = threadIdx.x;
  for (int e = tid; e < DIMX * 80; e += 320) {
    int r = e / 80, c = e % 80;
    Ws[r][c] = (c < DIMX) ? Wout[r * DIMX + c] : 0.f;
  }
  if (tid < 80) bs[tid] = (tid < DIMX) ? bout[tid] : 0.f;
  size_t row0 = (size_t)blockIdx.x * 32;
  for (int e = tid; e < 32 * DIMX; e += 320)
    as[e / DIMX][e % DIMX] = att[row0 * DIMX + e];
  __syncthreads();

  int r2 = tid / 20;   // 0..15 -> rows r2*2, r2*2+1
  int cq = tid % 20;   // 0..19 -> cols cq*4..cq*4+3 (last quad: 2 pad)
  int c0 = cq * 4;
  float acc0[4], acc1[4];
#pragma unroll
  for (int kk = 0; kk < 4; ++kk) { acc0[kk] = bs[c0 + kk]; acc1[kk] = bs[c0 + kk]; }

#pragma unroll 6
  for (int d = 0; d < DIMX; ++d) {
    float4 w = *(const float4*)&Ws[d][c0];
    float a0 = as[r2 * 2 + 0][d];
    float a1 = as[r2 * 2 + 1][d];
    acc0[0] = fmaf(a0, w.x, acc0[0]); acc0[1] = fmaf(a0, w.y, acc0[1]);
    acc0[2] = fmaf(a0, w.z, acc0[2]); acc0[3] = fmaf(a0, w.w, acc0[3]);
    acc1[0] = fmaf(a1, w.x, acc1[0]); acc1[1] = fmaf(a1, w.y, acc1[1]);
    acc1[2] = fmaf(a1, w.z, acc1[2]); acc1[3] = fmaf(a1, w.w, acc1[3]);
  }

  size_t r0o = (row0 + r2 * 2) * (size_t)DIMX;
  *(float2*)&out[r0o + c0]        = make_float2(acc0[0], acc0[1]);
  *(float2*)&out[r0o + DIMX + c0] = make_float2(acc1[0], acc1[1]);
  if (cq < 19) {
    *(float2*)&out[r0o + c0 + 2]        = make_float2(acc0[2], acc0[3]);
    *(float2*)&out[r0o + DIMX + c0 + 2] = make_float2(acc1[2], acc1[3]);
  }
}

extern "C" void kernel_launch(void* const* d_in, const int* in_sizes, int n_in,
                              void* d_out, int out_size, void* d_ws, size_t ws_size,
                              hipStream_t stream) {
  const float* x    = (const float*)d_in[0];
  const int*   mask = (const int*)d_in[1];
  const float* adj  = (const float*)d_in[2];
  const float* Wqkv = (const float*)d_in[3];
  const float* Wout = (const float*)d_in[4];
  const float* bout = (const float*)d_in[5];
  float* out = (float*)d_out;

  const size_t heads_rows = (size_t)BB * NH * NN;           // 49152
  float*   q   = (float*)d_ws;                              // heads_rows*QS f32
  float*   att = q + heads_rows * QS;                       // BB*NN*DIMX f32
  ushortx* kbf = (ushortx*)(att + (size_t)BB * NN * DIMX);  // heads_rows*KS ush
  ushortx* vbf = kbf + heads_rows * KS;

  const int NQ = 59;
  int qkv_threads = (BB * NN / 4) * NQ;
  qkv_kernel<<<(qkv_threads + 255) / 256, 256, 0, stream>>>(x, Wqkv, q, kbf, vbf);
  attn_kernel<<<BB * NH * (NN / 64), 256, 0, stream>>>(q, kbf, vbf, mask, adj, att);
  proj_kernel<<<BB * NN / 32, 320, 0, stream>>>(att, Wout, bout, out);
}

// Round 13
// 59.529 us; speedup vs baseline: 1.2392x; 1.0057x over previous
//
#include <hip/hip_runtime.h>
#include <hip/hip_bf16.h>
#include <cfloat>

#define BB 16
#define NN 512
#define DIMX 78
#define NH 6
#define DHH 13
#define QS 16                      // padded head-dim stride for q (f32)
#define KS 16                      // bf16 row stride (ushorts) for k/v
#define NC (NH*3*DHH)              // 234
#define SCALE 0.27735009811261457f // 13^-0.5
#define LAM_A 1.0f
#define LAM_G 0.5f
#define NU 32

typedef unsigned short ushortx;
typedef ushortx ushort8 __attribute__((ext_vector_type(8)));

__device__ __forceinline__ ushortx f2bf(float f) {
  unsigned u = __float_as_uint(f);
  unsigned r = (u + 0x7FFFu + ((u >> 16) & 1u)) >> 16;
  return (ushortx)r;
}
__device__ __forceinline__ float bf2f(ushortx h) {
  return __uint_as_float(((unsigned)h) << 16);
}

// ---------------- QKV projection: (B*N, 78) @ (78, 234) ----------------
// thread = 4 rows x 4 cols register tile; d chunked by 4 with float2 loads.
__global__ __launch_bounds__(256) void qkv_kernel(
    const float* __restrict__ x, const float* __restrict__ Wqkv,
    float* __restrict__ q, ushortx* __restrict__ kbf, ushortx* __restrict__ vbf) {
  int idx = blockIdx.x * 256 + threadIdx.x;
  const int NQ = 59;
  int rq = idx / NQ, cq = idx % NQ;
  if (rq >= (BB * NN) / 4) return;
  int c0 = cq * 4; if (c0 > NC - 4) c0 = NC - 4;  // c0 even -> float2 ok
  int r0 = rq * 4;
  const float* x0 = x + (size_t)r0 * DIMX;
  const float* wb = Wqkv + c0;

  float acc[4][4];
#pragma unroll
  for (int r = 0; r < 4; ++r)
#pragma unroll
    for (int c = 0; c < 4; ++c) acc[r][c] = 0.f;

#pragma unroll 2
  for (int d0 = 0; d0 < 76; d0 += 4) {
    float2 wA[4], wB[4];
#pragma unroll
    for (int dd = 0; dd < 4; ++dd) {
      wA[dd] = *(const float2*)(wb + (d0 + dd) * NC);
      wB[dd] = *(const float2*)(wb + (d0 + dd) * NC + 2);
    }
    float2 xv[4][2];
#pragma unroll
    for (int r = 0; r < 4; ++r) {
      xv[r][0] = *(const float2*)(x0 + r * DIMX + d0);
      xv[r][1] = *(const float2*)(x0 + r * DIMX + d0 + 2);
    }
#pragma unroll
    for (int dd = 0; dd < 4; ++dd) {
#pragma unroll
      for (int r = 0; r < 4; ++r) {
        float xvv = (dd < 2) ? ((dd & 1) ? xv[r][0].y : xv[r][0].x)
                             : ((dd & 1) ? xv[r][1].y : xv[r][1].x);
        acc[r][0] = fmaf(xvv, wA[dd].x, acc[r][0]);
        acc[r][1] = fmaf(xvv, wA[dd].y, acc[r][1]);
        acc[r][2] = fmaf(xvv, wB[dd].x, acc[r][2]);
        acc[r][3] = fmaf(xvv, wB[dd].y, acc[r][3]);
      }
    }
  }
  // tail d = 76, 77
#pragma unroll
  for (int dd = 0; dd < 2; ++dd) {
    int d = 76 + dd;
    float2 wA = *(const float2*)(wb + d * NC);
    float2 wB = *(const float2*)(wb + d * NC + 2);
#pragma unroll
    for (int r = 0; r < 4; ++r) {
      float xvv = x0[r * DIMX + d];
      acc[r][0] = fmaf(xvv, wA.x, acc[r][0]);
      acc[r][1] = fmaf(xvv, wA.y, acc[r][1]);
      acc[r][2] = fmaf(xvv, wB.x, acc[r][2]);
      acc[r][3] = fmaf(xvv, wB.y, acc[r][3]);
    }
  }

#pragma unroll
  for (int r = 0; r < 4; ++r) {
    int bn = r0 + r;
    int b = bn / NN, n = bn % NN;
#pragma unroll
    for (int c = 0; c < 4; ++c) {
      int col = c0 + c;
      int h  = col / (3 * DHH);
      int rm = col % (3 * DHH);
      int t  = rm / DHH;
      int dd = rm % DHH;
      size_t rowb = ((size_t)b * NH + h) * NN + n;
      if (t == 0)      q[rowb * QS + dd]   = acc[r][c];
      else if (t == 1) kbf[rowb * KS + dd] = f2bf(acc[r][c]);
      else             vbf[rowb * KS + dd] = f2bf(acc[r][c]);
    }
  }
}

// ---------------- Fused masked softmax attention (compacted, bf16 LDS) ----
// grid = 768 blocks; block = 256 (4 waves), 4 blocks/CU (LDS 38.4KB).
// R12 core + ONE change: q tile staged into LDS during the existing staging
// phase; per-iteration q reads become LDS broadcasts instead of exposed
// 400-900cy global loads.
__global__ __launch_bounds__(256, 4) void attn_kernel(
    const float* __restrict__ q, const ushortx* __restrict__ kbf,
    const ushortx* __restrict__ vbf, const int* __restrict__ mask,
    const float* __restrict__ adj, float* __restrict__ att) {
  __shared__ ushort8 k0s[NN], k1s[NN];
  __shared__ ushort8 v0s[NN], v1s[NN];
  __shared__ float qs[64][QS];  // q tile, f32 (4KB)
  __shared__ short jact[NN];
  __shared__ unsigned char ract[64];
  __shared__ float vsum[DHH];
  __shared__ float vpart_s[2][DHH];
  __shared__ int nact_s, nract_s;

  int d0    = blockIdx.x;
  int orig  = (d0 & 7) * 96 + (d0 >> 3);  // bijective: 768 = 8 XCDs * 96
  int itile = orig & 7;
  int bh    = orig >> 3;                  // b-major: bh = b*NH + h
  int b     = bh / NH;
  int h     = bh % NH;
  int i0    = itile * 64;

  const float*   qb  = q   + (size_t)bh * NN * QS;
  const ushortx* kbb = kbf + (size_t)bh * NN * KS;
  const ushortx* vbb = vbf + (size_t)bh * NN * KS;
  const int* mrow = mask + b * NN;

  int tid  = threadIdx.x;
  int wave = tid >> 6, lane = tid & 63;

  if (wave == 0) {
    // column compaction: lane owns 8 j's, prefix scan over lanes
    unsigned m8 = 0;
#pragma unroll
    for (int t = 0; t < 8; ++t) {
      int j = lane * 8 + t;
      if (mrow[j] != 0) m8 |= (1u << t);
    }
    int cnt = __popc(m8);
    int pre = cnt;
#pragma unroll
    for (int off = 1; off < 64; off <<= 1) {
      int o = __shfl_up(pre, off);
      if (lane >= off) pre += o;
    }
    pre -= cnt;
    int w = pre;
#pragma unroll
    for (int t = 0; t < 8; ++t)
      if ((m8 >> t) & 1) jact[w++] = (short)(lane * 8 + t);
    if (lane == 63) nact_s = pre + cnt;
  } else if (wave == 1) {
    // row compaction for this 64-row tile
    int a = (mrow[i0 + lane] != 0) ? 1 : 0;
    int pre = a;
#pragma unroll
    for (int off = 1; off < 64; off <<= 1) {
      int o = __shfl_up(pre, off);
      if (lane >= off) pre += o;
    }
    pre -= a;
    if (a) ract[pre] = (unsigned char)lane;
    if (lane == 63) nract_s = pre + a;
  } else {
    // waves 2,3: vsum partials over ALL 512 v rows (bf16 src, f32 accum)
    int idx2 = (wave - 2) * 64 + lane;  // 0..127
    float vp[DHH];
#pragma unroll
    for (int d = 0; d < DHH; ++d) vp[d] = 0.f;
#pragma unroll
    for (int rep = 0; rep < 4; ++rep) {
      const ushortx* vr = vbb + (size_t)(idx2 + rep * 128) * KS;
      ushort8 f0 = *(const ushort8*)(vr);
      ushort8 f1 = *(const ushort8*)(vr + 8);
#pragma unroll
      for (int d = 0; d < 8; ++d) vp[d] += bf2f(f0[d]);
#pragma unroll
      for (int d = 0; d < 5; ++d) vp[8 + d] += bf2f(f1[d]);
    }
#pragma unroll
    for (int off = 1; off < 64; off <<= 1)
#pragma unroll
      for (int d = 0; d < DHH; ++d) vp[d] += __shfl_xor(vp[d], off);
    if (lane < DHH) vpart_s[wave - 2][lane] = vp[lane];
  }
  __syncthreads();

  int na = nact_s;
  int nr = nract_s;

  // stage q tile: one float4 per thread, coalesced (hidden behind K/V staging)
  {
    int r = tid >> 2, c4 = (tid & 3) * 4;
    *(float4*)&qs[r][c4] = *(const float4*)(qb + (size_t)(i0 + r) * QS + c4);
  }
  // stage compacted K,V (straight 32B bf16 row copies); zero tails
  for (int t = tid; t < NN; t += 256) {
    if (t < na) {
      int j = jact[t];
      const ushortx* kr = kbb + (size_t)j * KS;
      const ushortx* vr = vbb + (size_t)j * KS;
      k0s[t] = *(const ushort8*)(kr);
      k1s[t] = *(const ushort8*)(kr + 8);
      v0s[t] = *(const ushort8*)(vr);
      v1s[t] = *(const ushort8*)(vr + 8);
    } else {
      ushort8 z = (ushort8)0;
      k0s[t] = z; k1s[t] = z; v0s[t] = z; v1s[t] = z;
      jact[t] = 0;
    }
  }
  if (tid < DHH) vsum[tid] = vpart_s[0][tid] + vpart_s[1][tid];
  __syncthreads();

  // fully-masked rows: uniform softmax over all 512, zero adjacency
  for (int e = tid; e < 64 * DHH; e += 256) {
    int r = e / DHH, d = e % DHH;
    int i = i0 + r;
    if (mrow[i] == 0)
      att[((size_t)b * NN + i) * DIMX + h * DHH + d] = (LAM_A / 512.f) * vsum[d];
  }

  int grp = lane >> 4;
  int li  = lane & 15;

  for (int base = wave * 4; base < nr; base += 16) {
    int ridx = base + grp;
    bool rok = ridx < nr;
    int rl = ract[rok ? ridx : 0];
    int i  = i0 + rl;
    const float* qi = &qs[rl][0];  // LDS broadcast (same addr per 16-lane grp)
    float qreg[DHH];
#pragma unroll
    for (int d = 0; d < DHH; ++d) qreg[d] = qi[d] * SCALE;
    const float* adjr = adj + ((size_t)b * NN + i) * NN;

    float s[NU], aj[NU];
    float mx = -FLT_MAX;
#pragma unroll
    for (int u = 0; u < NU; ++u) {
      if (u * 16 < na) {  // wave-uniform branch
        int t = u * 16 + li;
        ushort8 ka = k0s[t];
        ushort8 kc = k1s[t];
        aj[u] = adjr[jact[t]];  // prefetched, consumed after softmax
        float dot = 0.f;
#pragma unroll
        for (int d = 0; d < 8; ++d) dot = fmaf(qreg[d], bf2f(ka[d]), dot);
#pragma unroll
        for (int d = 0; d < 5; ++d) dot = fmaf(qreg[8 + d], bf2f(kc[d]), dot);
        s[u] = (t < na) ? dot : -FLT_MAX;
        mx = fmaxf(mx, s[u]);
      }
    }
#pragma unroll
    for (int off = 1; off < 16; off <<= 1) mx = fmaxf(mx, __shfl_xor(mx, off));

    float sum = 0.f;
#pragma unroll
    for (int u = 0; u < NU; ++u) {
      if (u * 16 < na) {
        float p = __expf(s[u] - mx);
        s[u] = p;
        sum += p;
      }
    }
#pragma unroll
    for (int off = 1; off < 16; off <<= 1) sum += __shfl_xor(sum, off);
    float inv = LAM_A / sum;

    float acc[DHH];
#pragma unroll
    for (int d = 0; d < DHH; ++d) acc[d] = 0.f;
#pragma unroll
    for (int u = 0; u < NU; ++u) {
      if (u * 16 < na) {
        int t = u * 16 + li;
        ushort8 va = v0s[t];
        ushort8 vc = v1s[t];
        float wu = fmaf(LAM_G, aj[u], s[u] * inv);  // tail rows: v==0 -> 0
#pragma unroll
        for (int d = 0; d < 8; ++d) acc[d] = fmaf(wu, bf2f(va[d]), acc[d]);
#pragma unroll
        for (int d = 0; d < 5; ++d) acc[8 + d] = fmaf(wu, bf2f(vc[d]), acc[8 + d]);
      }
    }
#pragma unroll
    for (int off = 1; off < 16; off <<= 1) {
#pragma unroll
      for (int d = 0; d < DHH; ++d) acc[d] += __shfl_xor(acc[d], off);
    }

    if (rok && li == 0) {
#pragma unroll
      for (int d = 0; d < DHH; ++d)
        att[((size_t)b * NN + i) * DIMX + h * DHH + d] = acc[d];
    }
  }
}

// ---------------- Output projection: (B*N,78) @ (78,78) + b ----------------
// block = 320 threads (5 waves), 32 rows/block, thread = 2 rows x 4 cols.
__global__ __launch_bounds__(320) void proj_kernel(
    const float* __restrict__ att, const float* __restrict__ Wout,
    const float* __restrict__ bout, float* __restrict__ out) {
  __shared__ float Ws[DIMX][80];   // padded cols
  __shared__ float as[32][82];     // stride 82: conflict-free row reads
  __shared__ float bs[80];
  int tid = threadIdx.x;
  for (int e = tid; e < DIMX * 80; e += 320) {
    int r = e / 80, c = e % 80;
    Ws[r][c] = (c < DIMX) ? Wout[r * DIMX + c] : 0.f;
  }
  if (tid < 80) bs[tid] = (tid < DIMX) ? bout[tid] : 0.f;
  size_t row0 = (size_t)blockIdx.x * 32;
  for (int e = tid; e < 32 * DIMX; e += 320)
    as[e / DIMX][e % DIMX] = att[row0 * DIMX + e];
  __syncthreads();

  int r2 = tid / 20;   // 0..15 -> rows r2*2, r2*2+1
  int cq = tid % 20;   // 0..19 -> cols cq*4..cq*4+3 (last quad: 2 pad)
  int c0 = cq * 4;
  float acc0[4], acc1[4];
#pragma unroll
  for (int kk = 0; kk < 4; ++kk) { acc0[kk] = bs[c0 + kk]; acc1[kk] = bs[c0 + kk]; }

#pragma unroll 6
  for (int d = 0; d < DIMX; ++d) {
    float4 w = *(const float4*)&Ws[d][c0];
    float a0 = as[r2 * 2 + 0][d];
    float a1 = as[r2 * 2 + 1][d];
    acc0[0] = fmaf(a0, w.x, acc0[0]); acc0[1] = fmaf(a0, w.y, acc0[1]);
    acc0[2] = fmaf(a0, w.z, acc0[2]); acc0[3] = fmaf(a0, w.w, acc0[3]);
    acc1[0] = fmaf(a1, w.x, acc1[0]); acc1[1] = fmaf(a1, w.y, acc1[1]);
    acc1[2] = fmaf(a1, w.z, acc1[2]); acc1[3] = fmaf(a1, w.w, acc1[3]);
  }

  size_t r0o = (row0 + r2 * 2) * (size_t)DIMX;
  *(float2*)&out[r0o + c0]        = make_float2(acc0[0], acc0[1]);
  *(float2*)&out[r0o + DIMX + c0] = make_float2(acc1[0], acc1[1]);
  if (cq < 19) {
    *(float2*)&out[r0o + c0 + 2]        = make_float2(acc0[2], acc0[3]);
    *(float2*)&out[r0o + DIMX + c0 + 2] = make_float2(acc1[2], acc1[3]);
  }
}

extern "C" void kernel_launch(void* const* d_in, const int* in_sizes, int n_in,
                              void* d_out, int out_size, void* d_ws, size_t ws_size,
                              hipStream_t stream) {
  const float* x    = (const float*)d_in[0];
  const int*   mask = (const int*)d_in[1];
  const float* adj  = (const float*)d_in[2];
  const float* Wqkv = (const float*)d_in[3];
  const float* Wout = (const float*)d_in[4];
  const float* bout = (const float*)d_in[5];
  float* out = (float*)d_out;

  const size_t heads_rows = (size_t)BB * NH * NN;           // 49152
  float*   q   = (float*)d_ws;                              // heads_rows*QS f32
  float*   att = q + heads_rows * QS;                       // BB*NN*DIMX f32
  ushortx* kbf = (ushortx*)(att + (size_t)BB * NN * DIMX);  // heads_rows*KS ush
  ushortx* vbf = kbf + heads_rows * KS;

  const int NQ = 59;
  int qkv_threads = (BB * NN / 4) * NQ;
  qkv_kernel<<<(qkv_threads + 255) / 256, 256, 0, stream>>>(x, Wqkv, q, kbf, vbf);
  attn_kernel<<<BB * NH * (NN / 64), 256, 0, stream>>>(q, kbf, vbf, mask, adj, att);
  proj_kernel<<<BB * NN / 32, 320, 0, stream>>>(att, Wout, bout, out);
}